// Round 1
// baseline (493.174 us; speedup 1.0000x reference)
//
#include <hip/hip_runtime.h>
#include <stdint.h>

#define M_ROWS 16384   // B*S
#define N_COLS 4096    // OUT
#define K_DIM  1024    // IN

typedef __bf16 bf16x8 __attribute__((ext_vector_type(8)));
typedef float  f32x4  __attribute__((ext_vector_type(4)));

// ---- async global->LDS, 16B per lane, LDS dest must be wave-uniform base ----
__device__ __forceinline__ void gload_lds16(const void* g, void* l) {
    __builtin_amdgcn_global_load_lds(
        (const __attribute__((address_space(1))) unsigned int*)g,
        (__attribute__((address_space(3))) unsigned int*)l, 16, 0, 0);
}

// bf16 truncation is exact here: all stored values are integers in [-256,256],
// whose fp32 bit patterns have zero low 16 bits.
__device__ __forceinline__ unsigned short f32_to_bf16_exact(float f) {
    return (unsigned short)(__builtin_bit_cast(unsigned int, f) >> 16);
}

// ---------------- kernel 1: per-block min/max of x ----------------
__global__ void k_minmax(const float4* __restrict__ x,
                         float* __restrict__ pmax, float* __restrict__ pmin) {
    const int n4 = (M_ROWS * K_DIM) / 4;  // 4194304
    float mx = -3.402823466e38f, mn = 3.402823466e38f;
    for (int i = blockIdx.x * blockDim.x + threadIdx.x; i < n4;
         i += gridDim.x * blockDim.x) {
        float4 v = x[i];
        mx = fmaxf(mx, fmaxf(fmaxf(v.x, v.y), fmaxf(v.z, v.w)));
        mn = fminf(mn, fminf(fminf(v.x, v.y), fminf(v.z, v.w)));
    }
#pragma unroll
    for (int off = 32; off > 0; off >>= 1) {
        mx = fmaxf(mx, __shfl_xor(mx, off));
        mn = fminf(mn, __shfl_xor(mn, off));
    }
    __shared__ float smx[4], smn[4];
    const int wave = threadIdx.x >> 6, lane = threadIdx.x & 63;
    if (lane == 0) { smx[wave] = mx; smn[wave] = mn; }
    __syncthreads();
    if (threadIdx.x == 0) {
        mx = fmaxf(fmaxf(smx[0], smx[1]), fmaxf(smx[2], smx[3]));
        mn = fminf(fminf(smn[0], smn[1]), fminf(smn[2], smn[3]));
        pmax[blockIdx.x] = mx;
        pmin[blockIdx.x] = mn;
    }
}

// ---------------- kernel 2: final scalars (scale, zp, alpha) ----------------
__global__ void k_scalars(const float* __restrict__ pmax, const float* __restrict__ pmin,
                          const float* __restrict__ w_scale, float* __restrict__ scal) {
    float mx = -3.402823466e38f, mn = 3.402823466e38f;
    for (int i = threadIdx.x; i < 2048; i += 256) {
        mx = fmaxf(mx, pmax[i]);
        mn = fminf(mn, pmin[i]);
    }
#pragma unroll
    for (int off = 32; off > 0; off >>= 1) {
        mx = fmaxf(mx, __shfl_xor(mx, off));
        mn = fminf(mn, __shfl_xor(mn, off));
    }
    __shared__ float smx[4], smn[4];
    const int wave = threadIdx.x >> 6, lane = threadIdx.x & 63;
    if (lane == 0) { smx[wave] = mx; smn[wave] = mn; }
    __syncthreads();
    if (threadIdx.x == 0) {
        mx = fmaxf(fmaxf(smx[0], smx[1]), fmaxf(smx[2], smx[3]));
        mn = fminf(fminf(smn[0], smn[1]), fminf(smn[2], smn[3]));
        const float scale = (mx - mn) / 255.0f;                       // (max-min)/QMAX
        const float zp = rintf((mx * -128.0f - mn * 127.0f) / (mx - mn));  // jnp.round == RNE
        scal[0] = scale;
        scal[1] = zp;
        scal[2] = scale * w_scale[0];  // alpha = x_scale * w_scale
    }
}

// ---------------- kernel 3: quantize x -> centered bf16 ----------------
__global__ void k_quant(const float4* __restrict__ x, const float* __restrict__ scal,
                        ushort4* __restrict__ xc) {
    const float scale = scal[0], zp = scal[1];
    const int n4 = (M_ROWS * K_DIM) / 4;
    for (int i = blockIdx.x * blockDim.x + threadIdx.x; i < n4;
         i += gridDim.x * blockDim.x) {
        float4 v = x[i];
        ushort4 o;
        {   // q = wrap_int8(rint(x/scale) + zp); store (float)q - zp as bf16 (exact)
            int q0 = (int)(rintf(v.x / scale) + zp);
            int q1 = (int)(rintf(v.y / scale) + zp);
            int q2 = (int)(rintf(v.z / scale) + zp);
            int q3 = (int)(rintf(v.w / scale) + zp);
            o.x = f32_to_bf16_exact((float)(signed char)q0 - zp);
            o.y = f32_to_bf16_exact((float)(signed char)q1 - zp);
            o.z = f32_to_bf16_exact((float)(signed char)q2 - zp);
            o.w = f32_to_bf16_exact((float)(signed char)q3 - zp);
        }
        xc[i] = o;
    }
}

// ---------------- kernel 4: center weights -> bf16 ----------------
__global__ void k_prepw(const int4* __restrict__ wq, const float* __restrict__ wzp,
                        ushort4* __restrict__ wc) {
    const float zp = wzp[0];
    const int n4 = (N_COLS * K_DIM) / 4;
    for (int i = blockIdx.x * blockDim.x + threadIdx.x; i < n4;
         i += gridDim.x * blockDim.x) {
        int4 v = wq[i];
        ushort4 o;
        o.x = f32_to_bf16_exact((float)v.x - zp);
        o.y = f32_to_bf16_exact((float)v.y - zp);
        o.z = f32_to_bf16_exact((float)v.z - zp);
        o.w = f32_to_bf16_exact((float)v.w - zp);
        wc[i] = o;
    }
}

// ---------------- kernel 5: bf16 B^T GEMM (m97 structure, 128x128x64) --------
// C[m,o] = (sum_k A[m,k]*B[o,k]) * alpha + bias[o]
__global__ void k_gemm(const unsigned short* __restrict__ A,
                       const unsigned short* __restrict__ B,
                       const float* __restrict__ scal,
                       const float* __restrict__ bias,
                       float* __restrict__ C) {
    __shared__ unsigned short As[128 * 64];
    __shared__ unsigned short Bs[128 * 64];

    const int tid = threadIdx.x;
    const int wave = tid >> 6, lane = tid & 63;

    // XCD-aware swizzle: nwg = 4096 = 8 * 512 (bijective)
    const int wg = blockIdx.x;
    const int swz = ((wg & 7) << 9) | (wg >> 3);
    const int bm = swz >> 5;   // 0..127  (M tiles)
    const int bn = swz & 31;   // 0..31   (N tiles)

    f32x4 acc[4][4];
#pragma unroll
    for (int i = 0; i < 4; ++i)
#pragma unroll
        for (int j = 0; j < 4; ++j)
#pragma unroll
            for (int r = 0; r < 4; ++r) acc[i][j][r] = 0.0f;

    const char* Ab = (const char*)(A + (size_t)bm * 128 * K_DIM);
    const char* Bb = (const char*)(B + (size_t)bn * 128 * K_DIM);
    const int colb = (lane & 7) << 4;        // byte col within 128B row-slice
    const int rsub = lane >> 3;              // row within 8-row chunk

    const int wr  = (wave >> 1) << 6;        // wave M origin: 0 / 64
    const int wc2 = (wave & 1) << 6;         // wave N origin: 0 / 64
    const int fr  = lane & 15;
    const int kg  = lane >> 4;

    for (int kt = 0; kt < K_DIM / 64; ++kt) {
        const int kb = kt * 128;             // byte offset of K-slice in a row
#pragma unroll
        for (int c = 0; c < 4; ++c) {
            const int chunk = c * 4 + wave;           // 0..15
            const int row = (chunk << 3) + rsub;      // 0..127
            const int lin = chunk << 10;              // LDS byte offset (wave-uniform)
            gload_lds16(Ab + (size_t)row * 2048 + kb + colb, (char*)As + lin);
            gload_lds16(Bb + (size_t)row * 2048 + kb + colb, (char*)Bs + lin);
        }
        asm volatile("s_waitcnt vmcnt(0)" ::: "memory");
        __syncthreads();

#pragma unroll
        for (int kk = 0; kk < 2; ++kk) {
            bf16x8 af[4], bf[4];
#pragma unroll
            for (int i = 0; i < 4; ++i) {
                af[i] = *(const bf16x8*)(As + (wr  + i * 16 + fr) * 64 + kk * 32 + kg * 8);
                bf[i] = *(const bf16x8*)(Bs + (wc2 + i * 16 + fr) * 64 + kk * 32 + kg * 8);
            }
#pragma unroll
            for (int i = 0; i < 4; ++i)
#pragma unroll
                for (int j = 0; j < 4; ++j)
                    acc[i][j] = __builtin_amdgcn_mfma_f32_16x16x32_bf16(
                        af[i], bf[j], acc[i][j], 0, 0, 0);
        }
        __syncthreads();
    }

    // epilogue: C/D layout col = lane&15, row = (lane>>4)*4 + r  [m89-verified]
    const float alpha = scal[2];
#pragma unroll
    for (int j = 0; j < 4; ++j) {
        const int gn = bn * 128 + wc2 + j * 16 + fr;
        const float bv = bias[gn];
#pragma unroll
        for (int i = 0; i < 4; ++i) {
            const int gm0 = bm * 128 + wr + i * 16 + kg * 4;
#pragma unroll
            for (int r = 0; r < 4; ++r)
                C[(size_t)(gm0 + r) * N_COLS + gn] = acc[i][j][r] * alpha + bv;
        }
    }
}

extern "C" void kernel_launch(void* const* d_in, const int* in_sizes, int n_in,
                              void* d_out, int out_size, void* d_ws, size_t ws_size,
                              hipStream_t stream) {
    const float* x    = (const float*)d_in[0];   // [8,2048,1024] f32
    const int*   wq   = (const int*)d_in[1];     // [4096,1024] int32 (int8 values)
    const float* wsc  = (const float*)d_in[2];   // scalar
    const float* wzp  = (const float*)d_in[3];   // scalar
    const float* bias = (const float*)d_in[4];   // [4096]
    float* out = (float*)d_out;                  // [8,2048,4096] f32

    // workspace layout (bytes)
    char* ws = (char*)d_ws;
    unsigned short* xc = (unsigned short*)(ws);              // 33,554,432 B
    unsigned short* wc = (unsigned short*)(ws + 33554432);   //  8,388,608 B
    float* pmax = (float*)(ws + 41943040);                   //  8 KB
    float* pmin = (float*)(ws + 41951232);                   //  8 KB
    float* scal = (float*)(ws + 41959424);                   //  scale, zp, alpha

    k_prepw  <<<2048, 256, 0, stream>>>((const int4*)wq, wzp, (ushort4*)wc);
    k_minmax <<<2048, 256, 0, stream>>>((const float4*)x, pmax, pmin);
    k_scalars<<<1,    256, 0, stream>>>(pmax, pmin, wsc, scal);
    k_quant  <<<2048, 256, 0, stream>>>((const float4*)x, scal, (ushort4*)xc);
    k_gemm   <<<4096, 256, 0, stream>>>(xc, wc, scal, bias, out);
}

// Round 2
// 469.875 us; speedup vs baseline: 1.0496x; 1.0496x over previous
//
#include <hip/hip_runtime.h>
#include <stdint.h>

#define M_ROWS 16384   // B*S
#define N_COLS 4096    // OUT
#define K_DIM  1024    // IN
#define NT     (K_DIM / 64)   // 16 K-tiles of BK=64

typedef __bf16 bf16x8 __attribute__((ext_vector_type(8)));
typedef float  f32x4  __attribute__((ext_vector_type(4)));

// ---- async global->LDS, 16B per lane, LDS dest is wave-uniform base + lane*16
__device__ __forceinline__ void gload_lds16(const void* g, void* l) {
    __builtin_amdgcn_global_load_lds(
        (const __attribute__((address_space(1))) unsigned int*)g,
        (__attribute__((address_space(3))) unsigned int*)l, 16, 0, 0);
}

// raw barrier pinned against compiler motion (rule #18/m201 pattern)
#define SBAR() do { __builtin_amdgcn_sched_barrier(0); \
                    __builtin_amdgcn_s_barrier();      \
                    __builtin_amdgcn_sched_barrier(0); } while (0)

// bf16 truncation is exact here: all stored values are integers in [-256,256].
__device__ __forceinline__ unsigned short f32_to_bf16_exact(float f) {
    return (unsigned short)(__builtin_bit_cast(unsigned int, f) >> 16);
}

// ---------------- kernel 1: per-block min/max of x ----------------
__global__ void k_minmax(const float4* __restrict__ x,
                         float* __restrict__ pmax, float* __restrict__ pmin) {
    const int n4 = (M_ROWS * K_DIM) / 4;
    float mx = -3.402823466e38f, mn = 3.402823466e38f;
    for (int i = blockIdx.x * blockDim.x + threadIdx.x; i < n4;
         i += gridDim.x * blockDim.x) {
        float4 v = x[i];
        mx = fmaxf(mx, fmaxf(fmaxf(v.x, v.y), fmaxf(v.z, v.w)));
        mn = fminf(mn, fminf(fminf(v.x, v.y), fminf(v.z, v.w)));
    }
#pragma unroll
    for (int off = 32; off > 0; off >>= 1) {
        mx = fmaxf(mx, __shfl_xor(mx, off));
        mn = fminf(mn, __shfl_xor(mn, off));
    }
    __shared__ float smx[4], smn[4];
    const int wave = threadIdx.x >> 6, lane = threadIdx.x & 63;
    if (lane == 0) { smx[wave] = mx; smn[wave] = mn; }
    __syncthreads();
    if (threadIdx.x == 0) {
        mx = fmaxf(fmaxf(smx[0], smx[1]), fmaxf(smx[2], smx[3]));
        mn = fminf(fminf(smn[0], smn[1]), fminf(smn[2], smn[3]));
        pmax[blockIdx.x] = mx;
        pmin[blockIdx.x] = mn;
    }
}

// ---------------- kernel 2: final scalars (scale, zp, alpha) ----------------
__global__ void k_scalars(const float* __restrict__ pmax, const float* __restrict__ pmin,
                          const float* __restrict__ w_scale, float* __restrict__ scal) {
    float mx = -3.402823466e38f, mn = 3.402823466e38f;
    for (int i = threadIdx.x; i < 2048; i += 256) {
        mx = fmaxf(mx, pmax[i]);
        mn = fminf(mn, pmin[i]);
    }
#pragma unroll
    for (int off = 32; off > 0; off >>= 1) {
        mx = fmaxf(mx, __shfl_xor(mx, off));
        mn = fminf(mn, __shfl_xor(mn, off));
    }
    __shared__ float smx[4], smn[4];
    const int wave = threadIdx.x >> 6, lane = threadIdx.x & 63;
    if (lane == 0) { smx[wave] = mx; smn[wave] = mn; }
    __syncthreads();
    if (threadIdx.x == 0) {
        mx = fmaxf(fmaxf(smx[0], smx[1]), fmaxf(smx[2], smx[3]));
        mn = fminf(fminf(smn[0], smn[1]), fminf(smn[2], smn[3]));
        const float scale = (mx - mn) / 255.0f;
        const float zp = rintf((mx * -128.0f - mn * 127.0f) / (mx - mn));
        scal[0] = scale;
        scal[1] = zp;
        scal[2] = scale * w_scale[0];
    }
}

// ---------------- kernel 3: quantize x -> centered bf16 ----------------
__global__ void k_quant(const float4* __restrict__ x, const float* __restrict__ scal,
                        ushort4* __restrict__ xc) {
    const float scale = scal[0], zp = scal[1];
    const int n4 = (M_ROWS * K_DIM) / 4;
    for (int i = blockIdx.x * blockDim.x + threadIdx.x; i < n4;
         i += gridDim.x * blockDim.x) {
        float4 v = x[i];
        ushort4 o;
        int q0 = (int)(rintf(v.x / scale) + zp);
        int q1 = (int)(rintf(v.y / scale) + zp);
        int q2 = (int)(rintf(v.z / scale) + zp);
        int q3 = (int)(rintf(v.w / scale) + zp);
        o.x = f32_to_bf16_exact((float)(signed char)q0 - zp);
        o.y = f32_to_bf16_exact((float)(signed char)q1 - zp);
        o.z = f32_to_bf16_exact((float)(signed char)q2 - zp);
        o.w = f32_to_bf16_exact((float)(signed char)q3 - zp);
        xc[i] = o;
    }
}

// ---------------- kernel 4: center weights -> bf16 ----------------
__global__ void k_prepw(const int4* __restrict__ wq, const float* __restrict__ wzp,
                        ushort4* __restrict__ wc) {
    const float zp = wzp[0];
    const int n4 = (N_COLS * K_DIM) / 4;
    for (int i = blockIdx.x * blockDim.x + threadIdx.x; i < n4;
         i += gridDim.x * blockDim.x) {
        int4 v = wq[i];
        ushort4 o;
        o.x = f32_to_bf16_exact((float)v.x - zp);
        o.y = f32_to_bf16_exact((float)v.y - zp);
        o.z = f32_to_bf16_exact((float)v.z - zp);
        o.w = f32_to_bf16_exact((float)v.w - zp);
        wc[i] = o;
    }
}

// ---------------- kernel 5: 256x256x64 8-phase bf16 GEMM ----------------
// C[m,o] = (sum_k A[m,k]*B[o,k]) * alpha + bias[o]
// 512 thr = 8 waves (2M x 4N); per-wave 128x64 out; LDS 128KiB double-buffered.
// LDS swizzle: phys_byte = logical ^ ((row&7)<<4)  (16B-granular -> gload_lds OK:
// linear LDS dest + inverse-swizzled GLOBAL source + swizzled ds_read addr).
// Counted vmcnt(4) gates: during tile t issue A(t+1) @phases 0,1 and B(t+2)
// @phases 2,3 (B region of buf[t&1] is free after phase 0's barrier since all
// B-frags are register-resident from phase 0). Newest 4 loads at the gate are
// B(t+2) -> vmcnt(4) proves tile t+1 fully landed. Tail drains vmcnt(0).
__global__ __launch_bounds__(512, 2)
void k_gemm(const unsigned short* __restrict__ A,
            const unsigned short* __restrict__ B,
            const float* __restrict__ scal,
            const float* __restrict__ bias,
            float* __restrict__ C) {
    __shared__ char lds[131072];  // A: buf b at b*32768 ; B: 65536 + b*32768

    const int tid  = threadIdx.x;
    const int wave = tid >> 6, lane = tid & 63;
    const int wm = wave >> 2, wn = wave & 3;     // 2 x 4 wave grid
    const int fr = lane & 15, kg = lane >> 4;

    // XCD-aware bijective swizzle: nwg = 1024 = 8 * 128
    const int wg  = blockIdx.x;
    const int swz = ((wg & 7) << 7) | (wg >> 3);
    const int bm  = swz >> 4;    // 0..63
    const int bn  = swz & 15;    // 0..15

    // ---- staging lane geometry (pre-swizzled global source) ----
    // lane's linear LDS 16B chunk within an 8KiB call: row=tid>>3, physcol=(tid&7)*16
    // logical col = physcol ^ ((row&7)<<4)
    const int scol = ((tid & 7) ^ ((tid >> 3) & 7)) << 4;
    const char* gA = (const char*)A + (size_t)(bm * 256 + (tid >> 3)) * (K_DIM * 2) + scol;
    const char* gB = (const char*)B + (size_t)(bn * 256 + (tid >> 3)) * (K_DIM * 2) + scol;

#define STAGE_A(tt, h, b) do {                                          \
        const char* g_ = gA + (size_t)(tt) * 128 + (size_t)(h) * 262144; \
        char* l_ = lds + (b) * 32768 + (h) * 16384 + wave * 1024;        \
        gload_lds16(g_, l_);                                             \
        gload_lds16(g_ + 131072, l_ + 8192);                             \
    } while (0)
#define STAGE_B(tt, h, b) do {                                          \
        const char* g_ = gB + (size_t)(tt) * 128 + (size_t)(h) * 262144; \
        char* l_ = lds + 65536 + (b) * 32768 + (h) * 16384 + wave * 1024; \
        gload_lds16(g_, l_);                                             \
        gload_lds16(g_ + 131072, l_ + 8192);                             \
    } while (0)

    // ---- fragment-read lane constants (swizzled) ----
    const int kx0 = ((kg * 16) ^ ((fr & 7) << 4));        // kk=0
    const int kx1 = ((64 + kg * 16) ^ ((fr & 7) << 4));   // kk=1
    const int arow = (wm * 128 + fr) * 128;               // byte base in A tile
    const int brow = (wn * 64 + fr) * 128;                // byte base in B tile

    f32x4 acc[8][4] = {};
    bf16x8 bf[4][2];

    // ---- prologue: tile0 (8 calls) + B(1) (4 calls); gate oldest 8 ----
    STAGE_A(0, 0, 0); STAGE_A(0, 1, 0);
    STAGE_B(0, 0, 0); STAGE_B(0, 1, 0);
    STAGE_B(1, 0, 1); STAGE_B(1, 1, 1);
    asm volatile("s_waitcnt vmcnt(4)" ::: "memory");
    SBAR();

    for (int t = 0; t < NT; ++t) {
        const int b = t & 1;
        const char* Ab = lds + b * 32768;
        const char* Bb = lds + 65536 + b * 32768;
#pragma unroll
        for (int q = 0; q < 4; ++q) {
            bf16x8 af[2][2];
            if (q == 0) {
#pragma unroll
                for (int j = 0; j < 4; ++j) {
                    bf[j][0] = *(const bf16x8*)(Bb + brow + j * 2048 + kx0);
                    bf[j][1] = *(const bf16x8*)(Bb + brow + j * 2048 + kx1);
                }
            }
#pragma unroll
            for (int i2 = 0; i2 < 2; ++i2) {
                const int i = 2 * q + i2;
                af[i2][0] = *(const bf16x8*)(Ab + arow + i * 2048 + kx0);
                af[i2][1] = *(const bf16x8*)(Ab + arow + i * 2048 + kx1);
            }
            // stage issue + per-tile gate
            if (q == 0)      { if (t + 1 < NT) STAGE_A(t + 1, 0, b ^ 1); }
            else if (q == 1) { if (t + 1 < NT) STAGE_A(t + 1, 1, b ^ 1); }
            else if (q == 2) { if (t + 2 < NT) STAGE_B(t + 2, 0, b); }
            else {
                if (t + 2 < NT) {
                    STAGE_B(t + 2, 1, b);
                    asm volatile("s_waitcnt vmcnt(4)" ::: "memory");
                } else {
                    asm volatile("s_waitcnt vmcnt(0)" ::: "memory");
                }
            }
            SBAR();
            __builtin_amdgcn_s_setprio(1);
#pragma unroll
            for (int kk = 0; kk < 2; ++kk)
#pragma unroll
                for (int i2 = 0; i2 < 2; ++i2)
#pragma unroll
                    for (int j = 0; j < 4; ++j)
                        acc[2 * q + i2][j] = __builtin_amdgcn_mfma_f32_16x16x32_bf16(
                            af[i2][kk], bf[j][kk], acc[2 * q + i2][j], 0, 0, 0);
            __builtin_amdgcn_s_setprio(0);
            SBAR();
        }
    }

    // ---- epilogue: C/D layout col=lane&15, row=(lane>>4)*4+r ----
    const float alpha = scal[2];
    const int gc_base = bn * 256 + wn * 64;
    const int gr_base = bm * 256 + wm * 128;
#pragma unroll
    for (int j = 0; j < 4; ++j) {
        const int gc = gc_base + j * 16 + fr;
        const float bv = bias[gc];
#pragma unroll
        for (int i = 0; i < 8; ++i) {
            const int gr0 = gr_base + i * 16 + kg * 4;
#pragma unroll
            for (int r = 0; r < 4; ++r)
                C[(size_t)(gr0 + r) * N_COLS + gc] = acc[i][j][r] * alpha + bv;
        }
    }
#undef STAGE_A
#undef STAGE_B
}

extern "C" void kernel_launch(void* const* d_in, const int* in_sizes, int n_in,
                              void* d_out, int out_size, void* d_ws, size_t ws_size,
                              hipStream_t stream) {
    const float* x    = (const float*)d_in[0];   // [8,2048,1024] f32
    const int*   wq   = (const int*)d_in[1];     // [4096,1024] int32 (int8 values)
    const float* wsc  = (const float*)d_in[2];   // scalar
    const float* wzp  = (const float*)d_in[3];   // scalar
    const float* bias = (const float*)d_in[4];   // [4096]
    float* out = (float*)d_out;                  // [8,2048,4096] f32

    char* ws = (char*)d_ws;
    unsigned short* xc = (unsigned short*)(ws);              // 33,554,432 B
    unsigned short* wc = (unsigned short*)(ws + 33554432);   //  8,388,608 B
    float* pmax = (float*)(ws + 41943040);
    float* pmin = (float*)(ws + 41951232);
    float* scal = (float*)(ws + 41959424);

    k_prepw  <<<2048, 256, 0, stream>>>((const int4*)wq, wzp, (ushort4*)wc);
    k_minmax <<<2048, 256, 0, stream>>>((const float4*)x, pmax, pmin);
    k_scalars<<<1,    256, 0, stream>>>(pmax, pmin, wsc, scal);
    k_quant  <<<2048, 256, 0, stream>>>((const float4*)x, scal, (ushort4*)xc);
    k_gemm   <<<1024, 512, 0, stream>>>(xc, wc, scal, bias, out);
}

// Round 3
// 407.447 us; speedup vs baseline: 1.2104x; 1.1532x over previous
//
#include <hip/hip_runtime.h>
#include <stdint.h>

#define M_ROWS 16384   // B*S
#define N_COLS 4096    // OUT
#define K_DIM  1024    // IN
#define NT     (K_DIM / 128)   // 8 K-tiles of BK=128 (int8)

typedef int   i32x4 __attribute__((ext_vector_type(4)));
typedef float f32x4 __attribute__((ext_vector_type(4)));

// ---- async global->LDS, 16B per lane, LDS dest is wave-uniform base + lane*16
__device__ __forceinline__ void gload_lds16(const void* g, void* l) {
    __builtin_amdgcn_global_load_lds(
        (const __attribute__((address_space(1))) unsigned int*)g,
        (__attribute__((address_space(3))) unsigned int*)l, 16, 0, 0);
}

// raw barrier pinned against compiler motion
#define SBAR() do { __builtin_amdgcn_sched_barrier(0); \
                    __builtin_amdgcn_s_barrier();      \
                    __builtin_amdgcn_sched_barrier(0); } while (0)

// ---------------- kernel 1: per-block min/max of x ----------------
__global__ void k_minmax(const float4* __restrict__ x,
                         float* __restrict__ pmax, float* __restrict__ pmin) {
    const int n4 = (M_ROWS * K_DIM) / 4;
    float mx = -3.402823466e38f, mn = 3.402823466e38f;
    for (int i = blockIdx.x * blockDim.x + threadIdx.x; i < n4;
         i += gridDim.x * blockDim.x) {
        float4 v = x[i];
        mx = fmaxf(mx, fmaxf(fmaxf(v.x, v.y), fmaxf(v.z, v.w)));
        mn = fminf(mn, fminf(fminf(v.x, v.y), fminf(v.z, v.w)));
    }
#pragma unroll
    for (int off = 32; off > 0; off >>= 1) {
        mx = fmaxf(mx, __shfl_xor(mx, off));
        mn = fminf(mn, __shfl_xor(mn, off));
    }
    __shared__ float smx[4], smn[4];
    const int wave = threadIdx.x >> 6, lane = threadIdx.x & 63;
    if (lane == 0) { smx[wave] = mx; smn[wave] = mn; }
    __syncthreads();
    if (threadIdx.x == 0) {
        mx = fmaxf(fmaxf(smx[0], smx[1]), fmaxf(smx[2], smx[3]));
        mn = fminf(fminf(smn[0], smn[1]), fminf(smn[2], smn[3]));
        pmax[blockIdx.x] = mx;
        pmin[blockIdx.x] = mn;
    }
}

// ---------------- kernel 2: final scalars (scale, zp, alpha) ----------------
__global__ void k_scalars(const float* __restrict__ pmax, const float* __restrict__ pmin,
                          const float* __restrict__ w_scale, float* __restrict__ scal) {
    float mx = -3.402823466e38f, mn = 3.402823466e38f;
    for (int i = threadIdx.x; i < 2048; i += 256) {
        mx = fmaxf(mx, pmax[i]);
        mn = fminf(mn, pmin[i]);
    }
#pragma unroll
    for (int off = 32; off > 0; off >>= 1) {
        mx = fmaxf(mx, __shfl_xor(mx, off));
        mn = fminf(mn, __shfl_xor(mn, off));
    }
    __shared__ float smx[4], smn[4];
    const int wave = threadIdx.x >> 6, lane = threadIdx.x & 63;
    if (lane == 0) { smx[wave] = mx; smn[wave] = mn; }
    __syncthreads();
    if (threadIdx.x == 0) {
        mx = fmaxf(fmaxf(smx[0], smx[1]), fmaxf(smx[2], smx[3]));
        mn = fminf(fminf(smn[0], smn[1]), fminf(smn[2], smn[3]));
        const float scale = (mx - mn) / 255.0f;
        const float zp = rintf((mx * -128.0f - mn * 127.0f) / (mx - mn));
        scal[0] = scale;
        scal[1] = zp;
        scal[2] = scale * w_scale[0];
    }
}

// ------- kernel 3: quantize x -> int8 + row sums (cm[m] = K*zx*zw - zw*sx[m])
// wave per row: lane owns x[row, lane*16 .. lane*16+15]
__global__ void k_quant(const float* __restrict__ x, const float* __restrict__ scal,
                        const float* __restrict__ wzp,
                        int4* __restrict__ xc8, float* __restrict__ cm) {
    const float scale = scal[0], zx = scal[1], zw = wzp[0];
    const int lane = threadIdx.x & 63;
    const int gw = (blockIdx.x * blockDim.x + threadIdx.x) >> 6;
    const int nw = (gridDim.x * blockDim.x) >> 6;
    for (int row = gw; row < M_ROWS; row += nw) {
        const float4* xr = (const float4*)(x + (size_t)row * K_DIM + lane * 16);
        union { signed char c[16]; int4 v; } u;
        int s = 0;
#pragma unroll
        for (int e = 0; e < 4; ++e) {
            float4 v = xr[e];
            signed char c0 = (signed char)(int)(rintf(v.x / scale) + zx);
            signed char c1 = (signed char)(int)(rintf(v.y / scale) + zx);
            signed char c2 = (signed char)(int)(rintf(v.z / scale) + zx);
            signed char c3 = (signed char)(int)(rintf(v.w / scale) + zx);
            u.c[e * 4 + 0] = c0; u.c[e * 4 + 1] = c1;
            u.c[e * 4 + 2] = c2; u.c[e * 4 + 3] = c3;
            s += (int)c0 + (int)c1 + (int)c2 + (int)c3;
        }
        xc8[row * 64 + lane] = u.v;
#pragma unroll
        for (int off = 32; off > 0; off >>= 1) s += __shfl_xor(s, off);
        if (lane == 0) cm[row] = zw * (1024.0f * zx - (float)s);
    }
}

// ------- kernel 4: pack weights -> int8 + row sums (cn[o] = -zx*sw[o]) -------
__global__ void k_prepw(const int* __restrict__ wq, const float* __restrict__ scal,
                        int4* __restrict__ wc8, float* __restrict__ cn) {
    const float zx = scal[1];
    const int lane = threadIdx.x & 63;
    const int gw = (blockIdx.x * blockDim.x + threadIdx.x) >> 6;
    const int nw = (gridDim.x * blockDim.x) >> 6;
    for (int row = gw; row < N_COLS; row += nw) {
        const int4* wr = (const int4*)(wq + (size_t)row * K_DIM + lane * 16);
        union { signed char c[16]; int4 v; } u;
        int s = 0;
#pragma unroll
        for (int e = 0; e < 4; ++e) {
            int4 v = wr[e];
            u.c[e * 4 + 0] = (signed char)v.x;
            u.c[e * 4 + 1] = (signed char)v.y;
            u.c[e * 4 + 2] = (signed char)v.z;
            u.c[e * 4 + 3] = (signed char)v.w;
            s += v.x + v.y + v.z + v.w;
        }
        wc8[row * 64 + lane] = u.v;
#pragma unroll
        for (int off = 32; off > 0; off >>= 1) s += __shfl_xor(s, off);
        if (lane == 0) cn[row] = -zx * (float)s;
    }
}

// ---------------- kernel 5: 256x256x128 8-phase int8 GEMM ----------------
// out[m,o] = (i32dot(x_q[m,:],w_q[o,:]) + cm[m] + cn[o]) * alpha + bias[o]
// Identical LDS geometry to the bf16 BK=64 version: rows are 128 B (=128 i8),
// same XOR swizzle phys = logical ^ ((row&7)<<4), same vmcnt(4) gating.
__global__ __launch_bounds__(512, 2)
void k_gemm(const signed char* __restrict__ A,
            const signed char* __restrict__ B,
            const float* __restrict__ scal,
            const float* __restrict__ bias,
            const float* __restrict__ cm,
            const float* __restrict__ cn,
            float* __restrict__ C) {
    __shared__ char lds[131072];  // A: b*32768 ; B: 65536 + b*32768

    const int tid  = threadIdx.x;
    const int wave = tid >> 6, lane = tid & 63;
    const int wm = wave >> 2, wn = wave & 3;
    const int fr = lane & 15, kg = lane >> 4;

    // XCD-aware bijective swizzle: nwg = 1024 = 8 * 128
    const int wg  = blockIdx.x;
    const int swz = ((wg & 7) << 7) | (wg >> 3);
    const int bm  = swz >> 4;    // 0..63
    const int bn  = swz & 15;    // 0..15

    // staging lane geometry (pre-swizzled global source), rows are 1024 B
    const int scol = ((tid & 7) ^ ((tid >> 3) & 7)) << 4;
    const char* gA = (const char*)A + (size_t)(bm * 256 + (tid >> 3)) * K_DIM + scol;
    const char* gB = (const char*)B + (size_t)(bn * 256 + (tid >> 3)) * K_DIM + scol;

#define STAGE_A(tt, h, b) do {                                           \
        const char* g_ = gA + (size_t)(tt) * 128 + (size_t)(h) * 131072; \
        char* l_ = lds + (b) * 32768 + (h) * 16384 + wave * 1024;        \
        gload_lds16(g_, l_);                                             \
        gload_lds16(g_ + 65536, l_ + 8192);                              \
    } while (0)
#define STAGE_B(tt, h, b) do {                                           \
        const char* g_ = gB + (size_t)(tt) * 128 + (size_t)(h) * 131072; \
        char* l_ = lds + 65536 + (b) * 32768 + (h) * 16384 + wave * 1024; \
        gload_lds16(g_, l_);                                             \
        gload_lds16(g_ + 65536, l_ + 8192);                              \
    } while (0)

    // fragment-read constants (swizzled); kk selects 64-byte K-half (K=64 i8)
    const int kx0 = ((kg * 16) ^ ((fr & 7) << 4));
    const int kx1 = ((64 + kg * 16) ^ ((fr & 7) << 4));
    const int arow = (wm * 128 + fr) * 128;
    const int brow = (wn * 64 + fr) * 128;

    i32x4 acc[8][4] = {};
    i32x4 bf[4][2];

    // prologue: tile0 (8 calls) + B(1) (4 calls); vmcnt(4) -> tile0 landed
    STAGE_A(0, 0, 0); STAGE_A(0, 1, 0);
    STAGE_B(0, 0, 0); STAGE_B(0, 1, 0);
    STAGE_B(1, 0, 1); STAGE_B(1, 1, 1);
    asm volatile("s_waitcnt vmcnt(4)" ::: "memory");
    SBAR();

    for (int t = 0; t < NT; ++t) {
        const int b = t & 1;
        const char* Ab = lds + b * 32768;
        const char* Bb = lds + 65536 + b * 32768;
#pragma unroll
        for (int q = 0; q < 4; ++q) {
            i32x4 af[2][2];
            if (q == 0) {
#pragma unroll
                for (int j = 0; j < 4; ++j) {
                    bf[j][0] = *(const i32x4*)(Bb + brow + j * 2048 + kx0);
                    bf[j][1] = *(const i32x4*)(Bb + brow + j * 2048 + kx1);
                }
            }
#pragma unroll
            for (int i2 = 0; i2 < 2; ++i2) {
                const int i = 2 * q + i2;
                af[i2][0] = *(const i32x4*)(Ab + arow + i * 2048 + kx0);
                af[i2][1] = *(const i32x4*)(Ab + arow + i * 2048 + kx1);
            }
            if (q == 0)      { if (t + 1 < NT) STAGE_A(t + 1, 0, b ^ 1); }
            else if (q == 1) { if (t + 1 < NT) STAGE_A(t + 1, 1, b ^ 1); }
            else if (q == 2) { if (t + 2 < NT) STAGE_B(t + 2, 0, b); }
            else {
                if (t + 2 < NT) {
                    STAGE_B(t + 2, 1, b);
                    asm volatile("s_waitcnt vmcnt(4)" ::: "memory");
                } else {
                    asm volatile("s_waitcnt vmcnt(0)" ::: "memory");
                }
            }
            SBAR();
            __builtin_amdgcn_s_setprio(1);
#pragma unroll
            for (int kk = 0; kk < 2; ++kk)
#pragma unroll
                for (int i2 = 0; i2 < 2; ++i2)
#pragma unroll
                    for (int j = 0; j < 4; ++j)
                        acc[2 * q + i2][j] = __builtin_amdgcn_mfma_i32_16x16x64_i8(
                            af[i2][kk], bf[j][kk], acc[2 * q + i2][j], 0, 0, 0);
            __builtin_amdgcn_s_setprio(0);
            SBAR();
        }
    }

    // epilogue: C/D layout col=lane&15, row=(lane>>4)*4+r (dtype-independent)
    const float alpha = scal[2];
    const int gc_base = bn * 256 + wn * 64;
    const int gr_base = bm * 256 + wm * 128;
    float bb[4], cc[4];
#pragma unroll
    for (int j = 0; j < 4; ++j) {
        const int gc = gc_base + j * 16 + fr;
        bb[j] = bias[gc];
        cc[j] = cn[gc];
    }
#pragma unroll
    for (int i = 0; i < 8; ++i) {
        const int gr0 = gr_base + i * 16 + kg * 4;
        const float4 cmv = *(const float4*)(cm + gr0);
#pragma unroll
        for (int j = 0; j < 4; ++j) {
            const int gc = gc_base + j * 16 + fr;
            C[(size_t)(gr0 + 0) * N_COLS + gc] = ((float)acc[i][j][0] + cmv.x + cc[j]) * alpha + bb[j];
            C[(size_t)(gr0 + 1) * N_COLS + gc] = ((float)acc[i][j][1] + cmv.y + cc[j]) * alpha + bb[j];
            C[(size_t)(gr0 + 2) * N_COLS + gc] = ((float)acc[i][j][2] + cmv.z + cc[j]) * alpha + bb[j];
            C[(size_t)(gr0 + 3) * N_COLS + gc] = ((float)acc[i][j][3] + cmv.w + cc[j]) * alpha + bb[j];
        }
    }
#undef STAGE_A
#undef STAGE_B
}

extern "C" void kernel_launch(void* const* d_in, const int* in_sizes, int n_in,
                              void* d_out, int out_size, void* d_ws, size_t ws_size,
                              hipStream_t stream) {
    const float* x    = (const float*)d_in[0];   // [8,2048,1024] f32
    const int*   wq   = (const int*)d_in[1];     // [4096,1024] int32 (int8 values)
    const float* wsc  = (const float*)d_in[2];   // scalar
    const float* wzp  = (const float*)d_in[3];   // scalar
    const float* bias = (const float*)d_in[4];   // [4096]
    float* out = (float*)d_out;                  // [8,2048,4096] f32

    char* ws = (char*)d_ws;
    int4*  xc8  = (int4*)(ws);                   // 16,777,216 B
    int4*  wc8  = (int4*)(ws + 16777216);        //  4,194,304 B
    float* cm   = (float*)(ws + 20971520);       //  65,536 B
    float* cn   = (float*)(ws + 21037056);       //  16,384 B
    float* pmax = (float*)(ws + 21053440);
    float* pmin = (float*)(ws + 21061632);
    float* scal = (float*)(ws + 21069824);

    k_minmax <<<2048, 256, 0, stream>>>((const float4*)x, pmax, pmin);
    k_scalars<<<1,    256, 0, stream>>>(pmax, pmin, wsc, scal);
    k_prepw  <<<1024, 256, 0, stream>>>(wq, scal, wc8, cn);
    k_quant  <<<2048, 256, 0, stream>>>(x, scal, wzp, xc8, cm);
    k_gemm   <<<1024, 512, 0, stream>>>((const signed char*)xc8, (const signed char*)wc8,
                                        scal, bias, cm, cn, out);
}